// Round 2
// baseline (236.587 us; speedup 1.0000x reference)
//
#include <hip/hip_runtime.h>

// Problem constants (from setup_inputs): B=8, N=2048, D=128.
#define BSZ   8
#define NN    2048
#define DD    128
#define NROWS (BSZ * NN)          // 16384
#define N4    (NN / 4)            // 512 float4 per row
#define P_A   0.8f
#define P_B   0.2f

// Clang native vector type — required by __builtin_nontemporal_load/store.
typedef float v4f __attribute__((ext_vector_type(4)));

// Kernel 1: per-row dot products, 2 rows per wave, float2 loads (8B/lane/row).
// si[row] = dot(x[row], W[0:128]) + bias ; sj[row] = dot(x[row], W[128:256])
__global__ __launch_bounds__(256) void row_dots(const float* __restrict__ x,
                                                const float* __restrict__ W,
                                                const float* __restrict__ bias,
                                                float* __restrict__ si,
                                                float* __restrict__ sj) {
    int gtid = blockIdx.x * blockDim.x + threadIdx.x;
    int wave = gtid >> 6;          // one wave handles rows 2w, 2w+1
    int lane = threadIdx.x & 63;
    int row0 = wave * 2;
    if (row0 >= NROWS) return;

    const float2* xr0 = (const float2*)(x + (size_t)row0 * DD);
    const float2* xr1 = (const float2*)(x + (size_t)(row0 + 1) * DD);
    const float2* W2  = (const float2*)W;

    float2 wi = W2[lane];          // W[2l], W[2l+1]        (si weights)
    float2 wj = W2[lane + 64];     // W[128+2l], W[129+2l]  (sj weights)
    float2 a0 = xr0[lane];
    float2 a1 = xr1[lane];

    float si0 = a0.x * wi.x + a0.y * wi.y;
    float sj0 = a0.x * wj.x + a0.y * wj.y;
    float si1 = a1.x * wi.x + a1.y * wi.y;
    float sj1 = a1.x * wj.x + a1.y * wj.y;

    #pragma unroll
    for (int off = 32; off > 0; off >>= 1) {
        si0 += __shfl_down(si0, off, 64);
        sj0 += __shfl_down(sj0, off, 64);
        si1 += __shfl_down(si1, off, 64);
        sj1 += __shfl_down(sj1, off, 64);
    }
    if (lane == 0) {
        float bb = bias[0];
        si[row0]     = si0 + bb;
        si[row0 + 1] = si1 + bb;
        sj[row0]     = sj0;
        sj[row0 + 1] = sj1;
    }
}

// Kernel 2: streaming fuse. 2048 blocks (8/CU, full occupancy); each block owns
// 8 contiguous output rows; per row: 256 threads x 2 float4.
// row is uniform per block-iteration -> si[row] is a scalar (s_load).
// adj/out are pure streams -> non-temporal to avoid L2/L3 thrash.
__global__ __launch_bounds__(256) void fuse_kernel(const v4f* __restrict__ adj,
                                                   const float* __restrict__ si,
                                                   const v4f* __restrict__ sj,
                                                   v4f* __restrict__ out) {
    const int tid = threadIdx.x;

    #pragma unroll 2
    for (int r = 0; r < 8; ++r) {
        const int row = blockIdx.x * 8 + r;       // SGPR-computable: uniform
        const int b   = row >> 11;                // N = 2048 = 2^11
        const float s = si[row];                  // scalar load, broadcast
        const v4f* sjrow = sj + (b << 9);         // 8 KB row, L1/L2 resident
        const size_t base = (size_t)row * N4;

        v4f sv0 = sjrow[tid];
        v4f sv1 = sjrow[tid + 256];
        v4f av0 = __builtin_nontemporal_load(adj + base + tid);
        v4f av1 = __builtin_nontemporal_load(adj + base + tid + 256);

        v4f o0, o1;
        o0.x = P_A * __builtin_amdgcn_rcpf(1.0f + __expf(-(s + sv0.x))) + P_B * av0.x;
        o0.y = P_A * __builtin_amdgcn_rcpf(1.0f + __expf(-(s + sv0.y))) + P_B * av0.y;
        o0.z = P_A * __builtin_amdgcn_rcpf(1.0f + __expf(-(s + sv0.z))) + P_B * av0.z;
        o0.w = P_A * __builtin_amdgcn_rcpf(1.0f + __expf(-(s + sv0.w))) + P_B * av0.w;
        o1.x = P_A * __builtin_amdgcn_rcpf(1.0f + __expf(-(s + sv1.x))) + P_B * av1.x;
        o1.y = P_A * __builtin_amdgcn_rcpf(1.0f + __expf(-(s + sv1.y))) + P_B * av1.y;
        o1.z = P_A * __builtin_amdgcn_rcpf(1.0f + __expf(-(s + sv1.z))) + P_B * av1.z;
        o1.w = P_A * __builtin_amdgcn_rcpf(1.0f + __expf(-(s + sv1.w))) + P_B * av1.w;

        __builtin_nontemporal_store(o0, out + base + tid);
        __builtin_nontemporal_store(o1, out + base + tid + 256);
    }
}

extern "C" void kernel_launch(void* const* d_in, const int* in_sizes, int n_in,
                              void* d_out, int out_size, void* d_ws, size_t ws_size,
                              hipStream_t stream) {
    const float* x    = (const float*)d_in[0];   // [B,N,D]
    const float* adj  = (const float*)d_in[1];   // [B,N,N]
    const float* W    = (const float*)d_in[2];   // [2D]
    const float* bias = (const float*)d_in[3];   // scalar

    float* si = (float*)d_ws;            // NROWS floats
    float* sj = si + NROWS;              // NROWS floats  (total 128 KiB)

    // Kernel 1: 16384 rows, 2 rows/wave, 4 waves/block -> 2048 blocks
    row_dots<<<NROWS / 8, 256, 0, stream>>>(x, W, bias, si, sj);

    // Kernel 2: 2048 blocks x 8 rows each = 16384 rows
    fuse_kernel<<<NROWS / 8, 256, 0, stream>>>(
        (const v4f*)adj, si, (const v4f*)sj, (v4f*)d_out);
}